// Round 1
// baseline (1107.859 us; speedup 1.0000x reference)
//
#include <hip/hip_runtime.h>
#include <math.h>

#define N1 50000
#define N2 50000
#define NE 640000
#define D 128
#define AD 64
#define EPSN 1e-8f

__device__ __forceinline__ float waveReduceSum(float v) {
    #pragma unroll
    for (int off = 32; off > 0; off >>= 1)
        v += __shfl_xor(v, off);
    return v;
}

// monotonic float<->uint encoding for atomicMax on floats
__device__ __forceinline__ unsigned encf(float f) {
    unsigned u = __float_as_uint(f);
    return (u & 0x80000000u) ? ~u : (u | 0x80000000u);
}
__device__ __forceinline__ float decf(unsigned x) {
    return __uint_as_float((x & 0x80000000u) ? (x & 0x7FFFFFFFu) : ~x);
}

// one wave per row: inv[i] = 1 / max(||X[i]||, eps)
__global__ void norms_kernel(const float* __restrict__ X, float* __restrict__ inv, int n) {
    int row = blockIdx.x * (blockDim.x >> 6) + (threadIdx.x >> 6);
    int lane = threadIdx.x & 63;
    if (row >= n) return;
    const float2* p = (const float2*)(X + (size_t)row * D);
    float2 v = p[lane];
    float s = waveReduceSum(v.x * v.x + v.y * v.y);
    if (lane == 0) inv[row] = 1.0f / fmaxf(sqrtf(s), EPSN);
}

// one wave per edge: sim[e] = cos(X1[src], X2[dst]); segmax via encoded atomicMax
__global__ void edge_sim_kernel(const float* __restrict__ X1, const float* __restrict__ X2,
                                const int* __restrict__ src, const int* __restrict__ dst,
                                const float* __restrict__ inv1, const float* __restrict__ inv2,
                                float* __restrict__ sim, unsigned* __restrict__ segmax) {
    int e = blockIdx.x * (blockDim.x >> 6) + (threadIdx.x >> 6);
    int lane = threadIdx.x & 63;
    if (e >= NE) return;
    int s = src[e], d = dst[e];
    const float2* p1 = (const float2*)(X1 + (size_t)s * D);
    const float2* p2 = (const float2*)(X2 + (size_t)d * D);
    float2 a = p1[lane];
    float2 b = p2[lane];
    float dot = waveReduceSum(a.x * b.x + a.y * b.y);
    if (lane == 0) {
        float sv = dot * inv1[s] * inv2[d];
        sim[e] = sv;
        atomicMax(&segmax[s], encf(sv));
    }
}

// one thread per edge: ex = exp(sim - segmax[src]); segsum += ex  (sim overwritten with ex)
__global__ void edge_exp_kernel(const int* __restrict__ src,
                                const unsigned* __restrict__ segmax,
                                float* __restrict__ sim, float* __restrict__ segsum) {
    int e = blockIdx.x * blockDim.x + threadIdx.x;
    if (e >= NE) return;
    int s = src[e];
    float ex = __expf(sim[e] - decf(segmax[s]));
    sim[e] = ex;
    atomicAdd(&segsum[s], ex);
}

// one wave per edge: out[src,:] += (ex/segsum[src]) * X2[dst,:]
__global__ void edge_agg_kernel(const float* __restrict__ X2,
                                const int* __restrict__ src, const int* __restrict__ dst,
                                const float* __restrict__ ex, const float* __restrict__ segsum,
                                float* __restrict__ out) {
    int e = blockIdx.x * (blockDim.x >> 6) + (threadIdx.x >> 6);
    int lane = threadIdx.x & 63;
    if (e >= NE) return;
    int s = src[e], d = dst[e];
    float w = ex[e] / segsum[s];
    const float2* p2 = (const float2*)(X2 + (size_t)d * D);
    float2 b = p2[lane];
    float* orow = out + (size_t)s * D + lane * 2;
    atomicAdd(&orow[0], w * b.x);
    atomicAdd(&orow[1], w * b.y);
}

// 2 nodes per 256-thread block; W_gate transposed into LDS (conflict-free reads)
__global__ __launch_bounds__(256) void gate_kernel(const float* __restrict__ Xn,
                                                   const float* __restrict__ Wg,
                                                   float* __restrict__ out) {
    __shared__ float WgT[AD][D];  // 32 KB
    for (int t = threadIdx.x; t < D * AD; t += 256) {
        int j = t >> 6, k = t & 63;  // Wg is [D][AD] row-major
        WgT[k][j] = Wg[t];
    }
    __syncthreads();
    int i = blockIdx.x * 2 + (threadIdx.x >> 7);
    int j = threadIdx.x & 127;
    if (i >= N1) return;
    const float* xr = Xn + (size_t)i * AD;
    float acc = 0.0f;
    #pragma unroll
    for (int k = 0; k < AD; ++k)
        acc += xr[k] * WgT[k][j];
    float g = 1.0f / (1.0f + __expf(-acc));
    size_t o = (size_t)i * D + j;
    out[o] = g * out[o];
}

extern "C" void kernel_launch(void* const* d_in, const int* in_sizes, int n_in,
                              void* d_out, int out_size, void* d_ws, size_t ws_size,
                              hipStream_t stream) {
    const float* X1 = (const float*)d_in[0];
    const float* X2 = (const float*)d_in[1];
    const float* Xn = (const float*)d_in[2];
    const int*   ci = (const int*)d_in[3];
    const float* Wg = (const float*)d_in[4];
    float* out = (float*)d_out;

    const int* src = ci;
    const int* dst = ci + NE;

    // workspace layout
    char* ws = (char*)d_ws;
    float*    inv1   = (float*)ws;                       ws += N1 * sizeof(float);
    float*    inv2   = (float*)ws;                       ws += N2 * sizeof(float);
    unsigned* segmax = (unsigned*)ws;                    ws += N1 * sizeof(unsigned);
    float*    segsum = (float*)ws;                       ws += N1 * sizeof(float);
    float*    sim    = (float*)ws;                       ws += NE * sizeof(float);

    // zero accumulators (agg lives in d_out; segmax encoding: 0 < enc(any finite float))
    hipMemsetAsync(d_out, 0, (size_t)N1 * D * sizeof(float), stream);
    hipMemsetAsync(segmax, 0, N1 * sizeof(unsigned), stream);
    hipMemsetAsync(segsum, 0, N1 * sizeof(float), stream);

    // 1. inverse norms
    norms_kernel<<<(N1 + 3) / 4, 256, 0, stream>>>(X1, inv1, N1);
    norms_kernel<<<(N2 + 3) / 4, 256, 0, stream>>>(X2, inv2, N2);

    // 2. per-edge cosine sim + segment max
    edge_sim_kernel<<<(NE + 3) / 4, 256, 0, stream>>>(X1, X2, src, dst, inv1, inv2, sim, segmax);

    // 3. exp + segment sum
    edge_exp_kernel<<<(NE + 255) / 256, 256, 0, stream>>>(src, segmax, sim, segsum);

    // 4. weighted scatter-aggregate into d_out
    edge_agg_kernel<<<(NE + 3) / 4, 256, 0, stream>>>(X2, src, dst, sim, segsum, out);

    // 5. gates * agg (in place)
    gate_kernel<<<(N1 + 1) / 2, 256, 0, stream>>>(Xn, Wg, out);
}

// Round 2
// 566.493 us; speedup vs baseline: 1.9556x; 1.9556x over previous
//
#include <hip/hip_runtime.h>
#include <math.h>

#define N1 50000
#define N2 50000
#define NE 640000
#define D 128
#define AD 64
#define EPSN 1e-8f

__device__ __forceinline__ float waveReduceSum(float v) {
    #pragma unroll
    for (int off = 32; off > 0; off >>= 1)
        v += __shfl_xor(v, off);
    return v;
}

// ---- CSR build ----------------------------------------------------------

__global__ void hist_kernel(const int* __restrict__ src, int* __restrict__ cnt) {
    int e = blockIdx.x * blockDim.x + threadIdx.x;
    if (e < NE) atomicAdd(&cnt[src[e]], 1);
}

// single-block exclusive scan over cnt[0..N1) -> rowptr[0..N1]
__global__ __launch_bounds__(1024) void scan_kernel(const int* __restrict__ cnt,
                                                    int* __restrict__ rowptr) {
    __shared__ int wsum[16];
    __shared__ int carry_s;
    int tid = threadIdx.x;
    int lane = tid & 63, wid = tid >> 6;
    if (tid == 0) carry_s = 0;
    __syncthreads();
    for (int base = 0; base < N1; base += 1024) {
        int idx = base + tid;
        int v = (idx < N1) ? cnt[idx] : 0;
        int x = v;  // inclusive wave scan
        #pragma unroll
        for (int off = 1; off < 64; off <<= 1) {
            int y = __shfl_up(x, off);
            if (lane >= off) x += y;
        }
        if (lane == 63) wsum[wid] = x;
        __syncthreads();
        if (wid == 0 && lane < 16) {
            int w = wsum[lane];
            #pragma unroll
            for (int off = 1; off < 16; off <<= 1) {
                int y = __shfl_up(w, off);
                if (lane >= off) w += y;
            }
            wsum[lane] = w;
        }
        __syncthreads();
        int waveoff = (wid > 0) ? wsum[wid - 1] : 0;
        int incl = x + waveoff + carry_s;
        if (idx < N1) rowptr[idx] = incl - v;  // exclusive
        __syncthreads();
        if (tid == 1023) carry_s = incl;
        __syncthreads();
    }
    if (tid == 0) rowptr[N1] = carry_s;
}

// scatter dst indices into CSR order; cursor starts as a copy of rowptr
__global__ void fill_kernel(const int* __restrict__ src, const int* __restrict__ dst,
                            int* __restrict__ cursor, int* __restrict__ csr_dst) {
    int e = blockIdx.x * blockDim.x + threadIdx.x;
    if (e < NE) {
        int p = atomicAdd(&cursor[src[e]], 1);
        csr_dst[p] = dst[e];
    }
}

// ---- X2 inverse norms ---------------------------------------------------

__global__ void norms_kernel(const float* __restrict__ X, float* __restrict__ inv, int n) {
    int row = blockIdx.x * (blockDim.x >> 6) + (threadIdx.x >> 6);
    int lane = threadIdx.x & 63;
    if (row >= n) return;
    const float2* p = (const float2*)(X + (size_t)row * D);
    float2 v = p[lane];
    float s = waveReduceSum(v.x * v.x + v.y * v.y);
    if (lane == 0) inv[row] = 1.0f / fmaxf(sqrtf(s), EPSN);
}

// ---- fused per-node pass: cosine sim + online softmax + weighted agg ----
// one wave per source node; X2 row gathers hit L2/L3 (X2 = 25.6 MB)
__global__ __launch_bounds__(256) void node_kernel(const float* __restrict__ X1,
                                                   const float* __restrict__ X2,
                                                   const int* __restrict__ rowptr,
                                                   const int* __restrict__ csr_dst,
                                                   const float* __restrict__ inv2,
                                                   float* __restrict__ out) {
    int i = blockIdx.x * 4 + (threadIdx.x >> 6);
    int lane = threadIdx.x & 63;
    if (i >= N1) return;
    const float2* p1 = (const float2*)(X1 + (size_t)i * D);
    float2 a = p1[lane];
    float nrm = waveReduceSum(a.x * a.x + a.y * a.y);
    float inv1 = 1.0f / fmaxf(sqrtf(nrm), EPSN);

    int e0 = rowptr[i], e1 = rowptr[i + 1];
    float m = -INFINITY, ssum = 0.0f;
    float accx = 0.0f, accy = 0.0f;
    const float2* X2p = (const float2*)X2;

    // 1-deep prefetch pipeline
    float2 bnx = make_float2(0.f, 0.f);
    float ivnx = 0.f;
    if (e0 < e1) {
        int dn = csr_dst[e0];
        bnx = X2p[(size_t)dn * 64 + lane];
        ivnx = inv2[dn];
    }
    for (int e = e0; e < e1; ++e) {
        float2 b = bnx;
        float iv2 = ivnx;
        if (e + 1 < e1) {
            int dn = csr_dst[e + 1];
            bnx = X2p[(size_t)dn * 64 + lane];
            ivnx = inv2[dn];
        }
        float dot = waveReduceSum(a.x * b.x + a.y * b.y);
        float sim = dot * inv1 * iv2;
        float mn = fmaxf(m, sim);
        float c = __expf(m - mn);    // 0 on first iter (m = -inf)
        float ex = __expf(sim - mn);
        ssum = ssum * c + ex;
        accx = accx * c + ex * b.x;
        accy = accy * c + ex * b.y;
        m = mn;
    }
    float invs = (ssum > 0.f) ? (1.0f / ssum) : 0.f;  // empty segment -> 0
    float2* orow = (float2*)(out + (size_t)i * D);
    orow[lane] = make_float2(accx * invs, accy * invs);
}

// ---- gates: sigmoid(Xn @ Wg^T) * out, in place --------------------------

__global__ __launch_bounds__(256) void gate_kernel(const float* __restrict__ Xn,
                                                   const float* __restrict__ Wg,
                                                   float* __restrict__ out) {
    __shared__ float WgT[AD][D];  // 32 KB, transposed for j-contiguous reads
    for (int t = threadIdx.x; t < D * AD; t += 256) {
        int j = t >> 6, k = t & 63;  // Wg is [D][AD] row-major
        WgT[k][j] = Wg[t];
    }
    __syncthreads();
    int i = blockIdx.x * 2 + (threadIdx.x >> 7);
    int j = threadIdx.x & 127;
    if (i >= N1) return;
    const float* xr = Xn + (size_t)i * AD;
    float acc = 0.0f;
    #pragma unroll
    for (int k = 0; k < AD; ++k)
        acc += xr[k] * WgT[k][j];
    float g = 1.0f / (1.0f + __expf(-acc));
    size_t o = (size_t)i * D + j;
    out[o] = g * out[o];
}

// ---- launch -------------------------------------------------------------

extern "C" void kernel_launch(void* const* d_in, const int* in_sizes, int n_in,
                              void* d_out, int out_size, void* d_ws, size_t ws_size,
                              hipStream_t stream) {
    const float* X1 = (const float*)d_in[0];
    const float* X2 = (const float*)d_in[1];
    const float* Xn = (const float*)d_in[2];
    const int*   ci = (const int*)d_in[3];
    const float* Wg = (const float*)d_in[4];
    float* out = (float*)d_out;

    const int* src = ci;
    const int* dst = ci + NE;

    char* ws = (char*)d_ws;
    int*   cnt     = (int*)ws;   ws += N1 * sizeof(int);
    int*   rowptr  = (int*)ws;   ws += (N1 + 1) * sizeof(int);
    int*   cursor  = (int*)ws;   ws += N1 * sizeof(int);
    int*   csr_dst = (int*)ws;   ws += NE * sizeof(int);
    float* inv2    = (float*)ws; ws += N2 * sizeof(float);

    hipMemsetAsync(cnt, 0, N1 * sizeof(int), stream);

    hist_kernel<<<(NE + 255) / 256, 256, 0, stream>>>(src, cnt);
    scan_kernel<<<1, 1024, 0, stream>>>(cnt, rowptr);
    hipMemcpyAsync(cursor, rowptr, N1 * sizeof(int), hipMemcpyDeviceToDevice, stream);
    fill_kernel<<<(NE + 255) / 256, 256, 0, stream>>>(src, dst, cursor, csr_dst);

    norms_kernel<<<(N2 + 3) / 4, 256, 0, stream>>>(X2, inv2, N2);

    node_kernel<<<(N1 + 3) / 4, 256, 0, stream>>>(X1, X2, rowptr, csr_dst, inv2, out);

    gate_kernel<<<(N1 + 1) / 2, 256, 0, stream>>>(Xn, Wg, out);
}

// Round 3
// 280.239 us; speedup vs baseline: 3.9533x; 2.0215x over previous
//
#include <hip/hip_runtime.h>
#include <math.h>

#define N1 50000
#define N2 50000
#define NE 640000
#define D 128
#define AD 64
#define EPSN 1e-8f

__device__ __forceinline__ float waveReduceSum(float v) {
    #pragma unroll
    for (int off = 32; off > 0; off >>= 1)
        v += __shfl_xor(v, off);
    return v;
}

// ---- CSR build ----------------------------------------------------------

__global__ void hist_kernel(const int* __restrict__ src, int* __restrict__ cnt) {
    int e = blockIdx.x * blockDim.x + threadIdx.x;
    if (e < NE) atomicAdd(&cnt[src[e]], 1);
}

// single-block exclusive scan over cnt[0..N1) -> rowptr[0..N1]
__global__ __launch_bounds__(1024) void scan_kernel(const int* __restrict__ cnt,
                                                    int* __restrict__ rowptr) {
    __shared__ int wsum[16];
    __shared__ int carry_s;
    int tid = threadIdx.x;
    int lane = tid & 63, wid = tid >> 6;
    if (tid == 0) carry_s = 0;
    __syncthreads();
    for (int base = 0; base < N1; base += 1024) {
        int idx = base + tid;
        int v = (idx < N1) ? cnt[idx] : 0;
        int x = v;  // inclusive wave scan
        #pragma unroll
        for (int off = 1; off < 64; off <<= 1) {
            int y = __shfl_up(x, off);
            if (lane >= off) x += y;
        }
        if (lane == 63) wsum[wid] = x;
        __syncthreads();
        if (wid == 0 && lane < 16) {
            int w = wsum[lane];
            #pragma unroll
            for (int off = 1; off < 16; off <<= 1) {
                int y = __shfl_up(w, off);
                if (lane >= off) w += y;
            }
            wsum[lane] = w;
        }
        __syncthreads();
        int waveoff = (wid > 0) ? wsum[wid - 1] : 0;
        int incl = x + waveoff + carry_s;
        if (idx < N1) rowptr[idx] = incl - v;  // exclusive
        __syncthreads();
        if (tid == 1023) carry_s = incl;
        __syncthreads();
    }
    if (tid == 0) rowptr[N1] = carry_s;
}

// scatter dst indices into CSR order; cursor starts as a copy of rowptr
__global__ void fill_kernel(const int* __restrict__ src, const int* __restrict__ dst,
                            int* __restrict__ cursor, int* __restrict__ csr_dst) {
    int e = blockIdx.x * blockDim.x + threadIdx.x;
    if (e < NE) {
        int p = atomicAdd(&cursor[src[e]], 1);
        csr_dst[p] = dst[e];
    }
}

// ---- X2 inverse norms ---------------------------------------------------

__global__ void norms_kernel(const float* __restrict__ X, float* __restrict__ inv, int n) {
    int row = blockIdx.x * (blockDim.x >> 6) + (threadIdx.x >> 6);
    int lane = threadIdx.x & 63;
    if (row >= n) return;
    const float2* p = (const float2*)(X + (size_t)row * D);
    float2 v = p[lane];
    float s = waveReduceSum(v.x * v.x + v.y * v.y);
    if (lane == 0) inv[row] = 1.0f / fmaxf(sqrtf(s), EPSN);
}

// ---- fused per-node pass: cosine sim + online softmax + weighted agg ----
// one wave per source node; X2 row gathers hit L2/L3 (X2 = 25.6 MB)
__global__ __launch_bounds__(256) void node_kernel(const float* __restrict__ X1,
                                                   const float* __restrict__ X2,
                                                   const int* __restrict__ rowptr,
                                                   const int* __restrict__ csr_dst,
                                                   const float* __restrict__ inv2,
                                                   float* __restrict__ out) {
    int i = blockIdx.x * 4 + (threadIdx.x >> 6);
    int lane = threadIdx.x & 63;
    if (i >= N1) return;
    const float2* p1 = (const float2*)(X1 + (size_t)i * D);
    float2 a = p1[lane];
    float nrm = waveReduceSum(a.x * a.x + a.y * a.y);
    float inv1 = 1.0f / fmaxf(sqrtf(nrm), EPSN);

    int e0 = rowptr[i], e1 = rowptr[i + 1];
    float m = -INFINITY, ssum = 0.0f;
    float accx = 0.0f, accy = 0.0f;
    const float2* X2p = (const float2*)X2;

    // 1-deep prefetch pipeline
    float2 bnx = make_float2(0.f, 0.f);
    float ivnx = 0.f;
    if (e0 < e1) {
        int dn = csr_dst[e0];
        bnx = X2p[(size_t)dn * 64 + lane];
        ivnx = inv2[dn];
    }
    for (int e = e0; e < e1; ++e) {
        float2 b = bnx;
        float iv2 = ivnx;
        if (e + 1 < e1) {
            int dn = csr_dst[e + 1];
            bnx = X2p[(size_t)dn * 64 + lane];
            ivnx = inv2[dn];
        }
        float dot = waveReduceSum(a.x * b.x + a.y * b.y);
        float sim = dot * inv1 * iv2;
        float mn = fmaxf(m, sim);
        float c = __expf(m - mn);    // 0 on first iter (m = -inf)
        float ex = __expf(sim - mn);
        ssum = ssum * c + ex;
        accx = accx * c + ex * b.x;
        accy = accy * c + ex * b.y;
        m = mn;
    }
    float invs = (ssum > 0.f) ? (1.0f / ssum) : 0.f;  // empty segment -> 0
    float2* orow = (float2*)(out + (size_t)i * D);
    orow[lane] = make_float2(accx * invs, accy * invs);
}

// ---- gates: sigmoid(Xn @ Wg^T) * out, in place --------------------------
// 32 nodes / 256-thread block. Wg staged transposed as float2 [64 k][64 j2]:
// LDS writes are lane-contiguous (conflict-free); the transpose gather is on
// the global-read side (Wg = 32 KB, L2-resident). Inner loop: shfl-broadcast
// of Xn + ds_read_b64 (lane-contiguous, conflict-free) + 2 FMA.
__global__ __launch_bounds__(256) void gate_kernel(const float* __restrict__ Xn,
                                                   const float* __restrict__ Wg,
                                                   float* __restrict__ out) {
    __shared__ float2 WgT2[AD][64];  // 32 KB: WgT2[k][j2] = (Wg[2j2][k], Wg[2j2+1][k])
    {
        int t = threadIdx.x;
        #pragma unroll
        for (int it = 0; it < 16; ++it, t += 256) {
            int k = t >> 6, j2 = t & 63;
            WgT2[k][j2] = make_float2(Wg[(size_t)(2 * j2) * AD + k],
                                      Wg[(size_t)(2 * j2 + 1) * AD + k]);
        }
    }
    __syncthreads();

    int j2 = threadIdx.x & 63;          // output pair (2*j2, 2*j2+1)
    int slot = threadIdx.x >> 6;        // 4 nodes in flight per iteration
    int ibase = blockIdx.x * 32;
    for (int n = 0; n < 8; ++n) {
        int i = ibase + n * 4 + slot;
        if (i >= N1) break;
        float xnv = Xn[(size_t)i * AD + j2];  // lane j2 holds Xn[i][j2]
        float acc0 = 0.f, acc1 = 0.f;
        #pragma unroll
        for (int k = 0; k < AD; ++k) {
            float xk = __shfl(xnv, k);
            float2 w = WgT2[k][j2];
            acc0 += xk * w.x;
            acc1 += xk * w.y;
        }
        float g0 = 1.0f / (1.0f + __expf(-acc0));
        float g1 = 1.0f / (1.0f + __expf(-acc1));
        float2* orow = (float2*)(out + (size_t)i * D);
        float2 o = orow[j2];
        orow[j2] = make_float2(g0 * o.x, g1 * o.y);
    }
}

// ---- launch -------------------------------------------------------------

extern "C" void kernel_launch(void* const* d_in, const int* in_sizes, int n_in,
                              void* d_out, int out_size, void* d_ws, size_t ws_size,
                              hipStream_t stream) {
    const float* X1 = (const float*)d_in[0];
    const float* X2 = (const float*)d_in[1];
    const float* Xn = (const float*)d_in[2];
    const int*   ci = (const int*)d_in[3];
    const float* Wg = (const float*)d_in[4];
    float* out = (float*)d_out;

    const int* src = ci;
    const int* dst = ci + NE;

    char* ws = (char*)d_ws;
    int*   cnt     = (int*)ws;   ws += N1 * sizeof(int);
    int*   rowptr  = (int*)ws;   ws += (N1 + 1) * sizeof(int);
    int*   cursor  = (int*)ws;   ws += N1 * sizeof(int);
    int*   csr_dst = (int*)ws;   ws += NE * sizeof(int);
    float* inv2    = (float*)ws; ws += N2 * sizeof(float);

    hipMemsetAsync(cnt, 0, N1 * sizeof(int), stream);

    hist_kernel<<<(NE + 255) / 256, 256, 0, stream>>>(src, cnt);
    scan_kernel<<<1, 1024, 0, stream>>>(cnt, rowptr);
    hipMemcpyAsync(cursor, rowptr, N1 * sizeof(int), hipMemcpyDeviceToDevice, stream);
    fill_kernel<<<(NE + 255) / 256, 256, 0, stream>>>(src, dst, cursor, csr_dst);

    norms_kernel<<<(N2 + 3) / 4, 256, 0, stream>>>(X2, inv2, N2);

    node_kernel<<<(N1 + 3) / 4, 256, 0, stream>>>(X1, X2, rowptr, csr_dst, inv2, out);

    gate_kernel<<<(N1 + 31) / 32, 256, 0, stream>>>(Xn, Wg, out);
}

// Round 4
// 216.252 us; speedup vs baseline: 5.1230x; 1.2959x over previous
//
#include <hip/hip_runtime.h>
#include <math.h>

#define N1 50000
#define N2 50000
#define NE 640000
#define D 128
#define AD 64
#define EPSN 1e-8f

#define SCAN_BLK 256
#define NSB ((N1 + SCAN_BLK - 1) / SCAN_BLK)  // 196

__device__ __forceinline__ float waveReduceSum(float v) {
    #pragma unroll
    for (int off = 32; off > 0; off >>= 1)
        v += __shfl_xor(v, off);
    return v;
}

// ---- CSR build ----------------------------------------------------------

__global__ void hist_kernel(const int* __restrict__ src, int* __restrict__ cnt) {
    int e = blockIdx.x * blockDim.x + threadIdx.x;
    if (e < NE) atomicAdd(&cnt[src[e]], 1);
}

// phase 1: per-block (256 elems) exclusive scan + block totals
__global__ __launch_bounds__(256) void scan1_kernel(const int* __restrict__ cnt,
                                                    int* __restrict__ rowptr,
                                                    int* __restrict__ bsum) {
    __shared__ int wsum[4];
    int tid = threadIdx.x, lane = tid & 63, wid = tid >> 6;
    int idx = blockIdx.x * SCAN_BLK + tid;
    int v = (idx < N1) ? cnt[idx] : 0;
    int x = v;  // inclusive wave scan
    #pragma unroll
    for (int off = 1; off < 64; off <<= 1) {
        int y = __shfl_up(x, off);
        if (lane >= off) x += y;
    }
    if (lane == 63) wsum[wid] = x;
    __syncthreads();
    if (tid == 0) {
        int s = 0;
        #pragma unroll
        for (int w = 0; w < 4; ++w) { int t = wsum[w]; wsum[w] = s; s += t; }
        bsum[blockIdx.x] = s;
    }
    __syncthreads();
    if (idx < N1) rowptr[idx] = x - v + wsum[wid];  // block-local exclusive
}

// phase 2: single-wave exclusive scan of the 196 block sums
__global__ __launch_bounds__(64) void scan2_kernel(int* __restrict__ bsum,
                                                   int* __restrict__ rowptr) {
    int lane = threadIdx.x;
    int carry = 0;
    for (int base = 0; base < NSB; base += 64) {
        int idx = base + lane;
        int v = (idx < NSB) ? bsum[idx] : 0;
        int x = v;
        #pragma unroll
        for (int off = 1; off < 64; off <<= 1) {
            int y = __shfl_up(x, off);
            if (lane >= off) x += y;
        }
        int tot = __shfl(x, 63);
        if (idx < NSB) bsum[idx] = x - v + carry;
        carry += tot;
    }
    if (lane == 0) rowptr[N1] = carry;
}

// phase 3: add block offsets
__global__ void scan3_kernel(int* __restrict__ rowptr, const int* __restrict__ bsum) {
    int idx = blockIdx.x * SCAN_BLK + threadIdx.x;
    if (idx < N1) rowptr[idx] += bsum[blockIdx.x];
}

// scatter dst indices into CSR order; cursor starts as a copy of rowptr
__global__ void fill_kernel(const int* __restrict__ src, const int* __restrict__ dst,
                            int* __restrict__ cursor, int* __restrict__ csr_dst) {
    int e = blockIdx.x * blockDim.x + threadIdx.x;
    if (e < NE) {
        int p = atomicAdd(&cursor[src[e]], 1);
        csr_dst[p] = dst[e];
    }
}

// ---- X2 inverse norms ---------------------------------------------------

__global__ void norms_kernel(const float* __restrict__ X, float* __restrict__ inv, int n) {
    int row = blockIdx.x * (blockDim.x >> 6) + (threadIdx.x >> 6);
    int lane = threadIdx.x & 63;
    if (row >= n) return;
    const float2* p = (const float2*)(X + (size_t)row * D);
    float2 v = p[lane];
    float s = waveReduceSum(v.x * v.x + v.y * v.y);
    if (lane == 0) inv[row] = 1.0f / fmaxf(sqrtf(s), EPSN);
}

// ---- pre-transpose W_gate: WgT2g[k*64+j2] = (Wg[2j2][k], Wg[2j2+1][k]) --

__global__ void wgT_kernel(const float* __restrict__ Wg, float2* __restrict__ WgT2g) {
    int t = blockIdx.x * 256 + threadIdx.x;  // t = k*64 + j2, t < 4096
    int k = t >> 6, j2 = t & 63;
    WgT2g[t] = make_float2(Wg[(size_t)(2 * j2) * AD + k],
                           Wg[(size_t)(2 * j2 + 1) * AD + k]);
}

// ---- fused per-node pass: cosine sim + online softmax + agg + gate ------
// one wave per source node, 8 nodes / 512-thread block (6250 blocks, no tail)
__global__ __launch_bounds__(512) void node_kernel(const float* __restrict__ X1,
                                                   const float* __restrict__ X2,
                                                   const int* __restrict__ rowptr,
                                                   const int* __restrict__ csr_dst,
                                                   const float* __restrict__ inv2,
                                                   const float2* __restrict__ WgT2g,
                                                   const float* __restrict__ Xn,
                                                   float* __restrict__ out) {
    __shared__ float2 WgT2[AD * 64];  // 32 KB, coalesced copy (conflict-free)
    for (int t = threadIdx.x; t < AD * 64; t += 512) WgT2[t] = WgT2g[t];
    __syncthreads();

    int i = blockIdx.x * 8 + (threadIdx.x >> 6);  // always < N1 (6250*8 == N1)
    int lane = threadIdx.x & 63;

    const float2* p1 = (const float2*)(X1 + (size_t)i * D);
    float2 a = p1[lane];
    float nrm = waveReduceSum(a.x * a.x + a.y * a.y);
    float inv1 = 1.0f / fmaxf(sqrtf(nrm), EPSN);

    int e0 = rowptr[i], e1 = rowptr[i + 1];
    float m = -INFINITY, ssum = 0.0f;
    float accx = 0.0f, accy = 0.0f;
    const float2* X2p = (const float2*)X2;

    // 1-deep prefetch pipeline over this node's edges
    float2 bnx = make_float2(0.f, 0.f);
    float ivnx = 0.f;
    if (e0 < e1) {
        int dn = csr_dst[e0];
        bnx = X2p[(size_t)dn * 64 + lane];
        ivnx = inv2[dn];
    }
    for (int e = e0; e < e1; ++e) {
        float2 b = bnx;
        float iv2 = ivnx;
        if (e + 1 < e1) {
            int dn = csr_dst[e + 1];
            bnx = X2p[(size_t)dn * 64 + lane];
            ivnx = inv2[dn];
        }
        float dot = waveReduceSum(a.x * b.x + a.y * b.y);
        float sim = dot * inv1 * iv2;
        float mn = fmaxf(m, sim);
        float c = __expf(m - mn);    // 0 on first iter (m = -inf)
        float ex = __expf(sim - mn);
        ssum = ssum * c + ex;
        accx = accx * c + ex * b.x;
        accy = accy * c + ex * b.y;
        m = mn;
    }
    float invs = (ssum > 0.f) ? (1.0f / ssum) : 0.f;  // empty segment -> 0

    // gate: lane j2 computes output columns (2*j2, 2*j2+1)
    float xnv = Xn[(size_t)i * AD + lane];  // lane k holds Xn[i][k]
    float acc0 = 0.f, acc1 = 0.f;
    #pragma unroll
    for (int k = 0; k < AD; ++k) {
        float xk = __shfl(xnv, k);
        float2 w = WgT2[k * 64 + lane];
        acc0 += xk * w.x;
        acc1 += xk * w.y;
    }
    float g0 = 1.0f / (1.0f + __expf(-acc0));
    float g1 = 1.0f / (1.0f + __expf(-acc1));

    float2* orow = (float2*)(out + (size_t)i * D);
    orow[lane] = make_float2(g0 * accx * invs, g1 * accy * invs);
}

// ---- launch -------------------------------------------------------------

extern "C" void kernel_launch(void* const* d_in, const int* in_sizes, int n_in,
                              void* d_out, int out_size, void* d_ws, size_t ws_size,
                              hipStream_t stream) {
    const float* X1 = (const float*)d_in[0];
    const float* X2 = (const float*)d_in[1];
    const float* Xn = (const float*)d_in[2];
    const int*   ci = (const int*)d_in[3];
    const float* Wg = (const float*)d_in[4];
    float* out = (float*)d_out;

    const int* src = ci;
    const int* dst = ci + NE;

    char* ws = (char*)d_ws;
    int*    cnt     = (int*)ws;    ws += N1 * sizeof(int);
    int*    rowptr  = (int*)ws;    ws += (N1 + 1) * sizeof(int);
    int*    cursor  = (int*)ws;    ws += N1 * sizeof(int);
    int*    csr_dst = (int*)ws;    ws += NE * sizeof(int);
    float*  inv2    = (float*)ws;  ws += N2 * sizeof(float);
    int*    bsum    = (int*)ws;    ws += NSB * sizeof(int);
    float2* WgT2g   = (float2*)ws; ws += AD * 64 * sizeof(float2);

    hipMemsetAsync(cnt, 0, N1 * sizeof(int), stream);

    wgT_kernel<<<16, 256, 0, stream>>>(Wg, WgT2g);
    hist_kernel<<<(NE + 255) / 256, 256, 0, stream>>>(src, cnt);
    scan1_kernel<<<NSB, SCAN_BLK, 0, stream>>>(cnt, rowptr, bsum);
    scan2_kernel<<<1, 64, 0, stream>>>(bsum, rowptr);
    scan3_kernel<<<NSB, SCAN_BLK, 0, stream>>>(rowptr, bsum);
    hipMemcpyAsync(cursor, rowptr, N1 * sizeof(int), hipMemcpyDeviceToDevice, stream);
    fill_kernel<<<(NE + 255) / 256, 256, 0, stream>>>(src, dst, cursor, csr_dst);

    norms_kernel<<<(N2 + 3) / 4, 256, 0, stream>>>(X2, inv2, N2);

    node_kernel<<<N1 / 8, 512, 0, stream>>>(X1, X2, rowptr, csr_dst, inv2, WgT2g, Xn, out);
}

// Round 5
// 207.502 us; speedup vs baseline: 5.3390x; 1.0422x over previous
//
#include <hip/hip_runtime.h>
#include <math.h>

#define N1 50000
#define N2 50000
#define NE 640000
#define D 128
#define AD 64
#define EPSN 1e-8f

#define SCAN_BLK 256
#define NSB ((N1 + SCAN_BLK - 1) / SCAN_BLK)  // 196
#define NORM_BLKS (N2 / 8)                    // 6250

// ---- fused preprocessing: Wg transpose | X2 inv-norms | zero cnt --------

__global__ __launch_bounds__(256) void pre_kernel(const float* __restrict__ Wg,
                                                  float2* __restrict__ WgT2g,
                                                  const float* __restrict__ X2,
                                                  float* __restrict__ inv2,
                                                  int* __restrict__ cnt) {
    int bid = blockIdx.x;
    if (bid < 16) {
        // WgT2g[k*64+j2] = (Wg[2j2][k], Wg[2j2+1][k]); Wg is [D][AD] row-major
        int t = bid * 256 + threadIdx.x;
        int k = t >> 6, j2 = t & 63;
        WgT2g[t] = make_float2(Wg[(size_t)(2 * j2) * AD + k],
                               Wg[(size_t)(2 * j2 + 1) * AD + k]);
    } else if (bid < 16 + NORM_BLKS) {
        int row = (bid - 16) * 8 + (threadIdx.x >> 5);  // < 50000 always
        int l32 = threadIdx.x & 31;
        float4 v = ((const float4*)(X2 + (size_t)row * D))[l32];
        float s = v.x * v.x + v.y * v.y + v.z * v.z + v.w * v.w;
        #pragma unroll
        for (int off = 16; off > 0; off >>= 1) s += __shfl_xor(s, off);
        if (l32 == 0) inv2[row] = 1.0f / fmaxf(sqrtf(s), EPSN);
    } else {
        int idx = (bid - 16 - NORM_BLKS) * 256 + threadIdx.x;
        if (idx < N1) cnt[idx] = 0;
    }
}

// ---- CSR build ----------------------------------------------------------

__global__ void hist_kernel(const int* __restrict__ src, int* __restrict__ cnt) {
    int e = blockIdx.x * blockDim.x + threadIdx.x;
    if (e < NE) atomicAdd(&cnt[src[e]], 1);
}

// phase 1: per-block (256 elems) exclusive scan + block totals
__global__ __launch_bounds__(256) void scan1_kernel(const int* __restrict__ cnt,
                                                    int* __restrict__ rowptr,
                                                    int* __restrict__ bsum) {
    __shared__ int wsum[4];
    int tid = threadIdx.x, lane = tid & 63, wid = tid >> 6;
    int idx = blockIdx.x * SCAN_BLK + tid;
    int v = (idx < N1) ? cnt[idx] : 0;
    int x = v;  // inclusive wave scan
    #pragma unroll
    for (int off = 1; off < 64; off <<= 1) {
        int y = __shfl_up(x, off);
        if (lane >= off) x += y;
    }
    if (lane == 63) wsum[wid] = x;
    __syncthreads();
    if (tid == 0) {
        int s = 0;
        #pragma unroll
        for (int w = 0; w < 4; ++w) { int t = wsum[w]; wsum[w] = s; s += t; }
        bsum[blockIdx.x] = s;
    }
    __syncthreads();
    if (idx < N1) rowptr[idx] = x - v + wsum[wid];  // block-local exclusive
}

// phase 2: single-wave exclusive scan of the 196 block sums
__global__ __launch_bounds__(64) void scan2_kernel(int* __restrict__ bsum,
                                                   int* __restrict__ rowptr) {
    int lane = threadIdx.x;
    int carry = 0;
    for (int base = 0; base < NSB; base += 64) {
        int idx = base + lane;
        int v = (idx < NSB) ? bsum[idx] : 0;
        int x = v;
        #pragma unroll
        for (int off = 1; off < 64; off <<= 1) {
            int y = __shfl_up(x, off);
            if (lane >= off) x += y;
        }
        int tot = __shfl(x, 63);
        if (idx < NSB) bsum[idx] = x - v + carry;
        carry += tot;
    }
    if (lane == 0) rowptr[N1] = carry;
}

// phase 3: add block offsets; also produce cursor copy for fill
__global__ void scan3_kernel(int* __restrict__ rowptr, const int* __restrict__ bsum,
                             int* __restrict__ cursor) {
    int idx = blockIdx.x * SCAN_BLK + threadIdx.x;
    if (idx < N1) {
        int v = rowptr[idx] + bsum[blockIdx.x];
        rowptr[idx] = v;
        cursor[idx] = v;
    }
}

// scatter dst indices into CSR order
__global__ void fill_kernel(const int* __restrict__ src, const int* __restrict__ dst,
                            int* __restrict__ cursor, int* __restrict__ csr_dst) {
    int e = blockIdx.x * blockDim.x + threadIdx.x;
    if (e < NE) {
        int p = atomicAdd(&cursor[src[e]], 1);
        csr_dst[p] = dst[e];
    }
}

// ---- fused per-node pass: cosine sim + online softmax + weighted agg ----
// One wave per source node; 2 edges in flight per iteration:
//   lanes 0-31 process even edges, lanes 32-63 odd edges, each half loading
//   a full 512B X2 row as float4 and running an independent online softmax.
//   One shfl_xor instruction reduces both halves' dots at once.
__global__ __launch_bounds__(256) void node_kernel(const float* __restrict__ X1,
                                                   const float* __restrict__ X2,
                                                   const int* __restrict__ rowptr,
                                                   const int* __restrict__ csr_dst,
                                                   const float* __restrict__ inv2,
                                                   float* __restrict__ out) {
    int i = blockIdx.x * 4 + (threadIdx.x >> 6);  // 12500*4 == N1, no tail
    int lane = threadIdx.x & 63;
    int half = lane >> 5, l32 = lane & 31;

    float4 a = ((const float4*)(X1 + (size_t)i * D))[l32];  // both halves: full row
    float s = a.x * a.x + a.y * a.y + a.z * a.z + a.w * a.w;
    #pragma unroll
    for (int off = 16; off > 0; off >>= 1) s += __shfl_xor(s, off);
    float inv1 = 1.0f / fmaxf(sqrtf(s), EPSN);

    int e0 = rowptr[i], e1 = rowptr[i + 1];
    float m = -INFINITY, ssum = 0.0f;
    float4 acc = make_float4(0.f, 0.f, 0.f, 0.f);
    const float4* X2p = (const float4*)X2;

    // 1-deep prefetch; this half's first edge
    int e = e0 + half;
    float4 b = make_float4(0.f, 0.f, 0.f, 0.f);
    float iv = 0.f;
    if (e < e1) { int dn = csr_dst[e]; b = X2p[(size_t)dn * 32 + l32]; iv = inv2[dn]; }

    for (int eb = e0; eb < e1; eb += 2) {
        float4 bc = b; float ivc = iv;
        int en = eb + 2 + half;
        if (en < e1) { int dn = csr_dst[en]; b = X2p[(size_t)dn * 32 + l32]; iv = inv2[dn]; }
        float pd = bc.x * a.x + bc.y * a.y + bc.z * a.z + bc.w * a.w;
        #pragma unroll
        for (int off = 16; off > 0; off >>= 1) pd += __shfl_xor(pd, off);
        if (eb + half < e1) {
            float sim = pd * inv1 * ivc;
            float mn = fmaxf(m, sim);
            float c = __expf(m - mn);    // 0 on this half's first edge
            float ex = __expf(sim - mn);
            ssum = ssum * c + ex;
            acc.x = acc.x * c + ex * bc.x;
            acc.y = acc.y * c + ex * bc.y;
            acc.z = acc.z * c + ex * bc.z;
            acc.w = acc.w * c + ex * bc.w;
            m = mn;
        }
    }

    // merge the two halves' online-softmax states
    float m_o  = __shfl_xor(m, 32);
    float ss_o = __shfl_xor(ssum, 32);
    float4 ao;
    ao.x = __shfl_xor(acc.x, 32);
    ao.y = __shfl_xor(acc.y, 32);
    ao.z = __shfl_xor(acc.z, 32);
    ao.w = __shfl_xor(acc.w, 32);
    float M = fmaxf(m, m_o);
    float cs = (m   > -INFINITY) ? __expf(m   - M) : 0.f;  // avoid exp(nan) on empty
    float co = (m_o > -INFINITY) ? __expf(m_o - M) : 0.f;
    float S = ssum * cs + ss_o * co;
    float invs = (S > 0.f) ? (1.0f / S) : 0.f;  // empty segment -> 0
    if (half == 0) {
        float4 r;
        r.x = (acc.x * cs + ao.x * co) * invs;
        r.y = (acc.y * cs + ao.y * co) * invs;
        r.z = (acc.z * cs + ao.z * co) * invs;
        r.w = (acc.w * cs + ao.w * co) * invs;
        ((float4*)(out + (size_t)i * D))[l32] = r;
    }
}

// ---- gates: sigmoid(Xn @ Wg^T) * out, in place --------------------------
// 32 nodes / 256-thread block; WgT2g copied coalesced into LDS (conflict-
// free), inner loop: shfl-broadcast of Xn + lane-contiguous ds_read_b64.
__global__ __launch_bounds__(256) void gate_kernel(const float* __restrict__ Xn,
                                                   const float2* __restrict__ WgT2g,
                                                   float* __restrict__ out) {
    __shared__ float2 WgT2[AD * 64];  // 32 KB
    for (int t = threadIdx.x; t < AD * 64; t += 256) WgT2[t] = WgT2g[t];
    __syncthreads();

    int j2 = threadIdx.x & 63;          // lane: output pair (2*j2, 2*j2+1)
    int slot = threadIdx.x >> 6;        // wave: one node per iteration
    int ibase = blockIdx.x * 32;
    for (int n = 0; n < 8; ++n) {
        int i = ibase + n * 4 + slot;
        if (i >= N1) break;
        float xnv = Xn[(size_t)i * AD + j2];  // lane k holds Xn[i][k]
        float acc0 = 0.f, acc1 = 0.f;
        #pragma unroll
        for (int k = 0; k < AD; ++k) {
            float xk = __shfl(xnv, k);
            float2 w = WgT2[k * 64 + j2];
            acc0 += xk * w.x;
            acc1 += xk * w.y;
        }
        float g0 = 1.0f / (1.0f + __expf(-acc0));
        float g1 = 1.0f / (1.0f + __expf(-acc1));
        float2* orow = (float2*)(out + (size_t)i * D);
        float2 o = orow[j2];
        orow[j2] = make_float2(g0 * o.x, g1 * o.y);
    }
}

// ---- launch -------------------------------------------------------------

extern "C" void kernel_launch(void* const* d_in, const int* in_sizes, int n_in,
                              void* d_out, int out_size, void* d_ws, size_t ws_size,
                              hipStream_t stream) {
    const float* X1 = (const float*)d_in[0];
    const float* X2 = (const float*)d_in[1];
    const float* Xn = (const float*)d_in[2];
    const int*   ci = (const int*)d_in[3];
    const float* Wg = (const float*)d_in[4];
    float* out = (float*)d_out;

    const int* src = ci;
    const int* dst = ci + NE;

    char* ws = (char*)d_ws;
    int*    cnt     = (int*)ws;    ws += N1 * sizeof(int);
    int*    rowptr  = (int*)ws;    ws += (N1 + 1) * sizeof(int);
    int*    cursor  = (int*)ws;    ws += N1 * sizeof(int);
    int*    csr_dst = (int*)ws;    ws += NE * sizeof(int);
    float*  inv2    = (float*)ws;  ws += N2 * sizeof(float);
    int*    bsum    = (int*)ws;    ws += NSB * sizeof(int);
    float2* WgT2g   = (float2*)ws; ws += AD * 64 * sizeof(float2);

    pre_kernel<<<16 + NORM_BLKS + NSB, 256, 0, stream>>>(Wg, WgT2g, X2, inv2, cnt);
    hist_kernel<<<(NE + 255) / 256, 256, 0, stream>>>(src, cnt);
    scan1_kernel<<<NSB, SCAN_BLK, 0, stream>>>(cnt, rowptr, bsum);
    scan2_kernel<<<1, 64, 0, stream>>>(bsum, rowptr);
    scan3_kernel<<<NSB, SCAN_BLK, 0, stream>>>(rowptr, bsum, cursor);
    fill_kernel<<<(NE + 255) / 256, 256, 0, stream>>>(src, dst, cursor, csr_dst);
    node_kernel<<<N1 / 4, 256, 0, stream>>>(X1, X2, rowptr, csr_dst, inv2, out);
    gate_kernel<<<(N1 + 31) / 32, 256, 0, stream>>>(Xn, WgT2g, out);
}

// Round 6
// 161.458 us; speedup vs baseline: 6.8616x; 1.2852x over previous
//
#include <hip/hip_runtime.h>
#include <math.h>

#define N1 50000
#define N2 50000
#define NE 640000
#define D 128
#define AD 64
#define EPSN 1e-8f

#define SCAN_BLK 256
#define NSB ((N1 + SCAN_BLK - 1) / SCAN_BLK)  // 196
#define NORM_BLKS (N2 / 8)                    // 6250

// ---- fused preprocessing: Wg transpose | X2 inv-norms | zero cnt --------

__global__ __launch_bounds__(256) void pre_kernel(const float* __restrict__ Wg,
                                                  float2* __restrict__ WgT2g,
                                                  const float* __restrict__ X2,
                                                  float* __restrict__ inv2,
                                                  int* __restrict__ cnt) {
    int bid = blockIdx.x;
    if (bid < 16) {
        // WgT2g[k*64+j2] = (Wg[2j2][k], Wg[2j2+1][k]); Wg is [D][AD] row-major
        int t = bid * 256 + threadIdx.x;
        int k = t >> 6, j2 = t & 63;
        WgT2g[t] = make_float2(Wg[(size_t)(2 * j2) * AD + k],
                               Wg[(size_t)(2 * j2 + 1) * AD + k]);
    } else if (bid < 16 + NORM_BLKS) {
        int row = (bid - 16) * 8 + (threadIdx.x >> 5);  // < 50000 always
        int l32 = threadIdx.x & 31;
        float4 v = ((const float4*)(X2 + (size_t)row * D))[l32];
        float s = v.x * v.x + v.y * v.y + v.z * v.z + v.w * v.w;
        #pragma unroll
        for (int off = 16; off > 0; off >>= 1) s += __shfl_xor(s, off);
        if (l32 == 0) inv2[row] = 1.0f / fmaxf(sqrtf(s), EPSN);
    } else {
        int idx = (bid - 16 - NORM_BLKS) * 256 + threadIdx.x;
        if (idx < N1) cnt[idx] = 0;
    }
}

// ---- CSR build ----------------------------------------------------------

__global__ void hist_kernel(const int* __restrict__ src, int* __restrict__ cnt) {
    int e = blockIdx.x * blockDim.x + threadIdx.x;
    if (e < NE) atomicAdd(&cnt[src[e]], 1);
}

// phase 1: per-block (256 elems) exclusive scan + block totals
__global__ __launch_bounds__(256) void scan1_kernel(const int* __restrict__ cnt,
                                                    int* __restrict__ rowptr,
                                                    int* __restrict__ bsum) {
    __shared__ int wsum[4];
    int tid = threadIdx.x, lane = tid & 63, wid = tid >> 6;
    int idx = blockIdx.x * SCAN_BLK + tid;
    int v = (idx < N1) ? cnt[idx] : 0;
    int x = v;  // inclusive wave scan
    #pragma unroll
    for (int off = 1; off < 64; off <<= 1) {
        int y = __shfl_up(x, off);
        if (lane >= off) x += y;
    }
    if (lane == 63) wsum[wid] = x;
    __syncthreads();
    if (tid == 0) {
        int s = 0;
        #pragma unroll
        for (int w = 0; w < 4; ++w) { int t = wsum[w]; wsum[w] = s; s += t; }
        bsum[blockIdx.x] = s;
    }
    __syncthreads();
    if (idx < N1) rowptr[idx] = x - v + wsum[wid];  // block-local exclusive
}

// phase 2: single-wave exclusive scan of the 196 block sums
__global__ __launch_bounds__(64) void scan2_kernel(int* __restrict__ bsum,
                                                   int* __restrict__ rowptr) {
    int lane = threadIdx.x;
    int carry = 0;
    for (int base = 0; base < NSB; base += 64) {
        int idx = base + lane;
        int v = (idx < NSB) ? bsum[idx] : 0;
        int x = v;
        #pragma unroll
        for (int off = 1; off < 64; off <<= 1) {
            int y = __shfl_up(x, off);
            if (lane >= off) x += y;
        }
        int tot = __shfl(x, 63);
        if (idx < NSB) bsum[idx] = x - v + carry;
        carry += tot;
    }
    if (lane == 0) rowptr[N1] = carry;
}

// phase 3: add block offsets; also produce cursor copy for fill
__global__ void scan3_kernel(int* __restrict__ rowptr, const int* __restrict__ bsum,
                             int* __restrict__ cursor) {
    int idx = blockIdx.x * SCAN_BLK + threadIdx.x;
    if (idx < N1) {
        int v = rowptr[idx] + bsum[blockIdx.x];
        rowptr[idx] = v;
        cursor[idx] = v;
    }
}

// scatter dst indices into CSR order
__global__ void fill_kernel(const int* __restrict__ src, const int* __restrict__ dst,
                            int* __restrict__ cursor, int* __restrict__ csr_dst) {
    int e = blockIdx.x * blockDim.x + threadIdx.x;
    if (e < NE) {
        int p = atomicAdd(&cursor[src[e]], 1);
        csr_dst[p] = dst[e];
    }
}

// ---- fused per-node pass: cosine sim + online softmax + weighted agg ----
// One wave per source node; 2 edges in flight per iteration:
//   lanes 0-31 process even edges, lanes 32-63 odd edges, each half loading
//   a full 512B X2 row as float4 and running an independent online softmax.
__global__ __launch_bounds__(256) void node_kernel(const float* __restrict__ X1,
                                                   const float* __restrict__ X2,
                                                   const int* __restrict__ rowptr,
                                                   const int* __restrict__ csr_dst,
                                                   const float* __restrict__ inv2,
                                                   float* __restrict__ out) {
    int i = blockIdx.x * 4 + (threadIdx.x >> 6);  // 12500*4 == N1, no tail
    int lane = threadIdx.x & 63;
    int half = lane >> 5, l32 = lane & 31;

    float4 a = ((const float4*)(X1 + (size_t)i * D))[l32];  // both halves: full row
    float s = a.x * a.x + a.y * a.y + a.z * a.z + a.w * a.w;
    #pragma unroll
    for (int off = 16; off > 0; off >>= 1) s += __shfl_xor(s, off);
    float inv1 = 1.0f / fmaxf(sqrtf(s), EPSN);

    int e0 = rowptr[i], e1 = rowptr[i + 1];
    float m = -INFINITY, ssum = 0.0f;
    float4 acc = make_float4(0.f, 0.f, 0.f, 0.f);
    const float4* X2p = (const float4*)X2;

    // 1-deep prefetch; this half's first edge
    int e = e0 + half;
    float4 b = make_float4(0.f, 0.f, 0.f, 0.f);
    float iv = 0.f;
    if (e < e1) { int dn = csr_dst[e]; b = X2p[(size_t)dn * 32 + l32]; iv = inv2[dn]; }

    for (int eb = e0; eb < e1; eb += 2) {
        float4 bc = b; float ivc = iv;
        int en = eb + 2 + half;
        if (en < e1) { int dn = csr_dst[en]; b = X2p[(size_t)dn * 32 + l32]; iv = inv2[dn]; }
        float pd = bc.x * a.x + bc.y * a.y + bc.z * a.z + bc.w * a.w;
        #pragma unroll
        for (int off = 16; off > 0; off >>= 1) pd += __shfl_xor(pd, off);
        if (eb + half < e1) {
            float sim = pd * inv1 * ivc;
            float mn = fmaxf(m, sim);
            float c = __expf(m - mn);    // 0 on this half's first edge
            float ex = __expf(sim - mn);
            ssum = ssum * c + ex;
            acc.x = acc.x * c + ex * bc.x;
            acc.y = acc.y * c + ex * bc.y;
            acc.z = acc.z * c + ex * bc.z;
            acc.w = acc.w * c + ex * bc.w;
            m = mn;
        }
    }

    // merge the two halves' online-softmax states
    float m_o  = __shfl_xor(m, 32);
    float ss_o = __shfl_xor(ssum, 32);
    float4 ao;
    ao.x = __shfl_xor(acc.x, 32);
    ao.y = __shfl_xor(acc.y, 32);
    ao.z = __shfl_xor(acc.z, 32);
    ao.w = __shfl_xor(acc.w, 32);
    float M = fmaxf(m, m_o);
    float cs = (m   > -INFINITY) ? __expf(m   - M) : 0.f;  // avoid exp(nan) on empty
    float co = (m_o > -INFINITY) ? __expf(m_o - M) : 0.f;
    float S = ssum * cs + ss_o * co;
    float invs = (S > 0.f) ? (1.0f / S) : 0.f;  // empty segment -> 0
    if (half == 0) {
        float4 r;
        r.x = (acc.x * cs + ao.x * co) * invs;
        r.y = (acc.y * cs + ao.y * co) * invs;
        r.z = (acc.z * cs + ao.z * co) * invs;
        r.w = (acc.w * cs + ao.w * co) * invs;
        ((float4*)(out + (size_t)i * D))[l32] = r;
    }
}

// ---- gates: sigmoid(Xn @ Wg^T) * out, in place --------------------------
// Register-tiled: each wave owns 16 nodes (4 groups of 4). Node index is
// wave-uniform (readfirstlane) so Xn[n][k] loads go through the SCALAR path
// (s_load, constant cache) — no DS, no VMEM in the loop. Per k: one
// conflict-free ds_read_b64 of WgT2[k][j2] + 8 FMAs (4 nodes x 2 cols).
__global__ __launch_bounds__(256) void gate_kernel(const float* __restrict__ Xn,
                                                   const float2* __restrict__ WgT2g,
                                                   float* __restrict__ out) {
    __shared__ float2 WgT2[AD * 64];  // 32 KB
    for (int t = threadIdx.x; t < AD * 64; t += 256) WgT2[t] = WgT2g[t];
    __syncthreads();

    int j2 = threadIdx.x & 63;  // lane: output columns (2*j2, 2*j2+1)
    int slot = __builtin_amdgcn_readfirstlane(threadIdx.x >> 6);
    int base = blockIdx.x * 64 + slot * 16;  // 782 blocks; 50000 % 16 == 0

    #pragma unroll
    for (int g = 0; g < 4; ++g) {
        int n0 = base + g * 4;
        if (n0 >= N1) break;  // wave-uniform tail guard
        const float* x0 = Xn + (size_t)n0 * AD;
        const float* x1 = x0 + AD;
        const float* x2 = x0 + 2 * AD;
        const float* x3 = x0 + 3 * AD;
        float a00 = 0.f, a01 = 0.f, a10 = 0.f, a11 = 0.f;
        float a20 = 0.f, a21 = 0.f, a30 = 0.f, a31 = 0.f;
        #pragma unroll
        for (int k = 0; k < AD; ++k) {
            float2 w = WgT2[k * 64 + j2];
            float v0 = x0[k], v1 = x1[k], v2 = x2[k], v3 = x3[k];
            a00 += v0 * w.x; a01 += v0 * w.y;
            a10 += v1 * w.x; a11 += v1 * w.y;
            a20 += v2 * w.x; a21 += v2 * w.y;
            a30 += v3 * w.x; a31 += v3 * w.y;
        }
        float g00 = 1.0f / (1.0f + __expf(-a00));
        float g01 = 1.0f / (1.0f + __expf(-a01));
        float g10 = 1.0f / (1.0f + __expf(-a10));
        float g11 = 1.0f / (1.0f + __expf(-a11));
        float g20 = 1.0f / (1.0f + __expf(-a20));
        float g21 = 1.0f / (1.0f + __expf(-a21));
        float g30 = 1.0f / (1.0f + __expf(-a30));
        float g31 = 1.0f / (1.0f + __expf(-a31));
        float2* o0 = (float2*)(out + (size_t)n0 * D);
        float2* o1 = (float2*)(out + (size_t)(n0 + 1) * D);
        float2* o2 = (float2*)(out + (size_t)(n0 + 2) * D);
        float2* o3 = (float2*)(out + (size_t)(n0 + 3) * D);
        float2 v0 = o0[j2], v1 = o1[j2], v2 = o2[j2], v3 = o3[j2];
        o0[j2] = make_float2(g00 * v0.x, g01 * v0.y);
        o1[j2] = make_float2(g10 * v1.x, g11 * v1.y);
        o2[j2] = make_float2(g20 * v2.x, g21 * v2.y);
        o3[j2] = make_float2(g30 * v3.x, g31 * v3.y);
    }
}

// ---- launch -------------------------------------------------------------

extern "C" void kernel_launch(void* const* d_in, const int* in_sizes, int n_in,
                              void* d_out, int out_size, void* d_ws, size_t ws_size,
                              hipStream_t stream) {
    const float* X1 = (const float*)d_in[0];
    const float* X2 = (const float*)d_in[1];
    const float* Xn = (const float*)d_in[2];
    const int*   ci = (const int*)d_in[3];
    const float* Wg = (const float*)d_in[4];
    float* out = (float*)d_out;

    const int* src = ci;
    const int* dst = ci + NE;

    char* ws = (char*)d_ws;
    int*    cnt     = (int*)ws;    ws += N1 * sizeof(int);
    int*    rowptr  = (int*)ws;    ws += (N1 + 1) * sizeof(int);
    int*    cursor  = (int*)ws;    ws += N1 * sizeof(int);
    int*    csr_dst = (int*)ws;    ws += NE * sizeof(int);
    float*  inv2    = (float*)ws;  ws += N2 * sizeof(float);
    int*    bsum    = (int*)ws;    ws += NSB * sizeof(int);
    float2* WgT2g   = (float2*)ws; ws += AD * 64 * sizeof(float2);

    pre_kernel<<<16 + NORM_BLKS + NSB, 256, 0, stream>>>(Wg, WgT2g, X2, inv2, cnt);
    hist_kernel<<<(NE + 255) / 256, 256, 0, stream>>>(src, cnt);
    scan1_kernel<<<NSB, SCAN_BLK, 0, stream>>>(cnt, rowptr, bsum);
    scan2_kernel<<<1, 64, 0, stream>>>(bsum, rowptr);
    scan3_kernel<<<NSB, SCAN_BLK, 0, stream>>>(rowptr, bsum, cursor);
    fill_kernel<<<(NE + 255) / 256, 256, 0, stream>>>(src, dst, cursor, csr_dst);
    node_kernel<<<N1 / 4, 256, 0, stream>>>(X1, X2, rowptr, csr_dst, inv2, out);
    gate_kernel<<<(N1 + 63) / 64, 256, 0, stream>>>(Xn, WgT2g, out);
}

// Round 7
// 143.331 us; speedup vs baseline: 7.7294x; 1.1265x over previous
//
#include <hip/hip_runtime.h>
#include <math.h>

#define N1 50000
#define N2 50000
#define NE 640000
#define D 128
#define AD 64
#define EPSN 1e-8f

#define SCAN_BLK 256
#define NSB ((N1 + SCAN_BLK - 1) / SCAN_BLK)  // 196
#define NORM_BLKS (N2 / 8)                    // 6250

__device__ __forceinline__ unsigned short f2bf(float f) {  // RNE f32->bf16
    unsigned u = __float_as_uint(f);
    u += 0x7FFFu + ((u >> 16) & 1u);
    return (unsigned short)(u >> 16);
}
__device__ __forceinline__ float bflo(unsigned u) { return __uint_as_float(u << 16); }
__device__ __forceinline__ float bfhi(unsigned u) { return __uint_as_float(u & 0xFFFF0000u); }

// ---- preprocessing: Wg transpose | X2 inv-norms + bf16 copy | zero cnt --

__global__ __launch_bounds__(256) void pre_kernel(const float* __restrict__ Wg,
                                                  float2* __restrict__ WgT2g,
                                                  const float* __restrict__ X2,
                                                  float* __restrict__ inv2,
                                                  ushort4* __restrict__ X2b,
                                                  int* __restrict__ cnt) {
    int bid = blockIdx.x;
    if (bid < 16) {
        // WgT2g[k*64+j2] = (Wg[2j2][k], Wg[2j2+1][k]); Wg is [D][AD] row-major
        int t = bid * 256 + threadIdx.x;
        int k = t >> 6, j2 = t & 63;
        WgT2g[t] = make_float2(Wg[(size_t)(2 * j2) * AD + k],
                               Wg[(size_t)(2 * j2 + 1) * AD + k]);
    } else if (bid < 16 + NORM_BLKS) {
        int row = (bid - 16) * 8 + (threadIdx.x >> 5);  // < 50000 always
        int l32 = threadIdx.x & 31;
        float4 v = ((const float4*)(X2 + (size_t)row * D))[l32];
        // bf16 copy (rows of 128 bf16 = 32 ushort4 per row)
        ushort4 bv;
        bv.x = f2bf(v.x); bv.y = f2bf(v.y); bv.z = f2bf(v.z); bv.w = f2bf(v.w);
        X2b[(size_t)row * 32 + l32] = bv;
        float s = v.x * v.x + v.y * v.y + v.z * v.z + v.w * v.w;
        #pragma unroll
        for (int off = 16; off > 0; off >>= 1) s += __shfl_xor(s, off);
        if (l32 == 0) inv2[row] = 1.0f / fmaxf(sqrtf(s), EPSN);
    } else {
        int idx = (bid - 16 - NORM_BLKS) * 256 + threadIdx.x;
        if (idx < N1) cnt[idx] = 0;
    }
}

// ---- CSR build ----------------------------------------------------------

__global__ void hist_kernel(const int* __restrict__ src, int* __restrict__ cnt) {
    int e = blockIdx.x * blockDim.x + threadIdx.x;
    if (e < NE) atomicAdd(&cnt[src[e]], 1);
}

// phase 1: per-block (256 elems) exclusive scan + block totals
__global__ __launch_bounds__(256) void scan1_kernel(const int* __restrict__ cnt,
                                                    int* __restrict__ rowptr,
                                                    int* __restrict__ bsum) {
    __shared__ int wsum[4];
    int tid = threadIdx.x, lane = tid & 63, wid = tid >> 6;
    int idx = blockIdx.x * SCAN_BLK + tid;
    int v = (idx < N1) ? cnt[idx] : 0;
    int x = v;  // inclusive wave scan
    #pragma unroll
    for (int off = 1; off < 64; off <<= 1) {
        int y = __shfl_up(x, off);
        if (lane >= off) x += y;
    }
    if (lane == 63) wsum[wid] = x;
    __syncthreads();
    if (tid == 0) {
        int s = 0;
        #pragma unroll
        for (int w = 0; w < 4; ++w) { int t = wsum[w]; wsum[w] = s; s += t; }
        bsum[blockIdx.x] = s;
    }
    __syncthreads();
    if (idx < N1) rowptr[idx] = x - v + wsum[wid];  // block-local exclusive
}

// phase 2+3 fused: each block computes its own bsum prefix (<=196 ints),
// adds it, and writes rowptr + cursor. Last block also writes rowptr[N1].
__global__ __launch_bounds__(256) void scan23_kernel(int* __restrict__ rowptr,
                                                     const int* __restrict__ bsum,
                                                     int* __restrict__ cursor) {
    __shared__ int wsum[4];
    __shared__ int pref_s;
    int tid = threadIdx.x, lane = tid & 63, wid = tid >> 6;
    int bid = blockIdx.x;
    // sum of bsum[0..bid)  (bid <= 195 < 256: one element per thread)
    int v = (tid < bid) ? bsum[tid] : 0;
    #pragma unroll
    for (int off = 32; off > 0; off >>= 1) v += __shfl_xor(v, off);
    if (lane == 0) wsum[wid] = v;
    __syncthreads();
    if (tid == 0) {
        int p = wsum[0] + wsum[1] + wsum[2] + wsum[3];
        pref_s = p;
        if (bid == NSB - 1) rowptr[N1] = p + bsum[NSB - 1];
    }
    __syncthreads();
    int prefix = pref_s;
    int idx = bid * SCAN_BLK + tid;
    if (idx < N1) {
        int r = rowptr[idx] + prefix;
        rowptr[idx] = r;
        cursor[idx] = r;
    }
}

// scatter dst indices into CSR order
__global__ void fill_kernel(const int* __restrict__ src, const int* __restrict__ dst,
                            int* __restrict__ cursor, int* __restrict__ csr_dst) {
    int e = blockIdx.x * blockDim.x + threadIdx.x;
    if (e < NE) {
        int p = atomicAdd(&cursor[src[e]], 1);
        csr_dst[p] = dst[e];
    }
}

// ---- fused per-node pass: cosine sim + softmax + weighted agg -----------
// One wave per source node; 4 edges in flight (16 lanes per edge, each lane
// holding 8 bf16 columns). sim = cos() is bounded in [-1,1], so softmax
// needs NO max subtraction: exp(sim) in [0.37, 2.72] is perfectly
// conditioned and exp(sim)/sum == reference's exp(sim-max)/sum exactly.
__global__ __launch_bounds__(256) void node_kernel(const float* __restrict__ X1,
                                                   const ushort4* __restrict__ X2b,
                                                   const int* __restrict__ rowptr,
                                                   const int* __restrict__ csr_dst,
                                                   const float* __restrict__ inv2,
                                                   float* __restrict__ out) {
    int i = blockIdx.x * 4 + (threadIdx.x >> 6);  // 12500*4 == N1, no tail
    int lane = threadIdx.x & 63;
    int q = lane >> 4, l16 = lane & 15;  // quarter q owns edge eb+q

    // lane covers columns 8*l16 .. 8*l16+7 (all 4 quarters replicate the row)
    const float4* p1 = (const float4*)(X1 + (size_t)i * D);
    float4 a0 = p1[2 * l16], a1 = p1[2 * l16 + 1];
    float s = a0.x * a0.x + a0.y * a0.y + a0.z * a0.z + a0.w * a0.w
            + a1.x * a1.x + a1.y * a1.y + a1.z * a1.z + a1.w * a1.w;
    #pragma unroll
    for (int off = 8; off > 0; off >>= 1) s += __shfl_xor(s, off);
    float inv1 = 1.0f / fmaxf(sqrtf(s), EPSN);

    int e0 = rowptr[i], e1 = rowptr[i + 1];
    float ssum = 0.0f;
    float4 acc0 = make_float4(0.f, 0.f, 0.f, 0.f);
    float4 acc1 = make_float4(0.f, 0.f, 0.f, 0.f);

    // 1-deep prefetch; this quarter's first edge (row = 16 x uint4 of bf16)
    const uint4* X2p = (const uint4*)X2b;
    uint4 braw = make_uint4(0u, 0u, 0u, 0u);
    float iv = 0.f;
    {
        int e = e0 + q;
        if (e < e1) { int dn = csr_dst[e]; braw = X2p[(size_t)dn * 16 + l16]; iv = inv2[dn]; }
    }

    for (int eb = e0; eb < e1; eb += 4) {
        uint4 bc = braw; float ivc = iv;
        int en = eb + 4 + q;
        if (en < e1) { int dn = csr_dst[en]; braw = X2p[(size_t)dn * 16 + l16]; iv = inv2[dn]; }
        float b0 = bflo(bc.x), b1 = bfhi(bc.x), b2 = bflo(bc.y), b3 = bfhi(bc.y);
        float b4 = bflo(bc.z), b5 = bfhi(bc.z), b6 = bflo(bc.w), b7 = bfhi(bc.w);
        float pd = a0.x * b0 + a0.y * b1 + a0.z * b2 + a0.w * b3
                 + a1.x * b4 + a1.y * b5 + a1.z * b6 + a1.w * b7;
        #pragma unroll
        for (int off = 8; off > 0; off >>= 1) pd += __shfl_xor(pd, off);
        if (eb + q < e1) {
            float ex = __expf(pd * inv1 * ivc);
            ssum += ex;
            acc0.x += ex * b0; acc0.y += ex * b1; acc0.z += ex * b2; acc0.w += ex * b3;
            acc1.x += ex * b4; acc1.y += ex * b5; acc1.z += ex * b6; acc1.w += ex * b7;
        }
    }

    // sum the 4 quarter states (no max bookkeeping needed)
    #pragma unroll
    for (int off = 16; off <= 32; off <<= 1) {
        ssum   += __shfl_xor(ssum, off);
        acc0.x += __shfl_xor(acc0.x, off); acc0.y += __shfl_xor(acc0.y, off);
        acc0.z += __shfl_xor(acc0.z, off); acc0.w += __shfl_xor(acc0.w, off);
        acc1.x += __shfl_xor(acc1.x, off); acc1.y += __shfl_xor(acc1.y, off);
        acc1.z += __shfl_xor(acc1.z, off); acc1.w += __shfl_xor(acc1.w, off);
    }
    float invs = (ssum > 0.f) ? (1.0f / ssum) : 0.f;  // empty segment -> 0
    if (lane < 16) {
        float4* orow = (float4*)(out + (size_t)i * D);
        orow[2 * l16]     = make_float4(acc0.x * invs, acc0.y * invs, acc0.z * invs, acc0.w * invs);
        orow[2 * l16 + 1] = make_float4(acc1.x * invs, acc1.y * invs, acc1.z * invs, acc1.w * invs);
    }
}

// ---- gates: sigmoid(Xn @ Wg^T) * out, in place --------------------------
// Register-tiled; node index wave-uniform (readfirstlane) -> Xn loads go
// through the scalar path. Per k: one conflict-free ds_read_b64 + 8 FMAs.
__global__ __launch_bounds__(256) void gate_kernel(const float* __restrict__ Xn,
                                                   const float2* __restrict__ WgT2g,
                                                   float* __restrict__ out) {
    __shared__ float2 WgT2[AD * 64];  // 32 KB
    for (int t = threadIdx.x; t < AD * 64; t += 256) WgT2[t] = WgT2g[t];
    __syncthreads();

    int j2 = threadIdx.x & 63;  // lane: output columns (2*j2, 2*j2+1)
    int slot = __builtin_amdgcn_readfirstlane(threadIdx.x >> 6);
    int base = blockIdx.x * 64 + slot * 16;  // 782 blocks

    #pragma unroll
    for (int g = 0; g < 4; ++g) {
        int n0 = base + g * 4;
        if (n0 >= N1) break;  // wave-uniform tail guard
        const float* x0 = Xn + (size_t)n0 * AD;
        const float* x1 = x0 + AD;
        const float* x2 = x0 + 2 * AD;
        const float* x3 = x0 + 3 * AD;
        float a00 = 0.f, a01 = 0.f, a10 = 0.f, a11 = 0.f;
        float a20 = 0.f, a21 = 0.f, a30 = 0.f, a31 = 0.f;
        #pragma unroll
        for (int k = 0; k < AD; ++k) {
            float2 w = WgT2[k * 64 + j2];
            float v0 = x0[k], v1 = x1[k], v2 = x2[k], v3 = x3[k];
            a00 += v0 * w.x; a01 += v0 * w.y;
            a10 += v1 * w.x; a11 += v1 * w.y;
            a20 += v2 * w.x; a21 += v2 * w.y;
            a30 += v3 * w.x; a31 += v3 * w.y;
        }
        float g00 = 1.0f / (1.0f + __expf(-a00));
        float g01 = 1.0f / (1.0f + __expf(-a01));
        float g10 = 1.0f / (1.0f + __expf(-a10));
        float g11 = 1.0f / (1.0f + __expf(-a11));
        float g20 = 1.0f / (1.0f + __expf(-a20));
        float g21 = 1.0f / (1.0f + __expf(-a21));
        float g30 = 1.0f / (1.0f + __expf(-a30));
        float g31 = 1.0f / (1.0f + __expf(-a31));
        float2* o0 = (float2*)(out + (size_t)n0 * D);
        float2* o1 = (float2*)(out + (size_t)(n0 + 1) * D);
        float2* o2 = (float2*)(out + (size_t)(n0 + 2) * D);
        float2* o3 = (float2*)(out + (size_t)(n0 + 3) * D);
        float2 v0 = o0[j2], v1 = o1[j2], v2 = o2[j2], v3 = o3[j2];
        o0[j2] = make_float2(g00 * v0.x, g01 * v0.y);
        o1[j2] = make_float2(g10 * v1.x, g11 * v1.y);
        o2[j2] = make_float2(g20 * v2.x, g21 * v2.y);
        o3[j2] = make_float2(g30 * v3.x, g31 * v3.y);
    }
}

// ---- launch -------------------------------------------------------------

extern "C" void kernel_launch(void* const* d_in, const int* in_sizes, int n_in,
                              void* d_out, int out_size, void* d_ws, size_t ws_size,
                              hipStream_t stream) {
    const float* X1 = (const float*)d_in[0];
    const float* X2 = (const float*)d_in[1];
    const float* Xn = (const float*)d_in[2];
    const int*   ci = (const int*)d_in[3];
    const float* Wg = (const float*)d_in[4];
    float* out = (float*)d_out;

    const int* src = ci;
    const int* dst = ci + NE;

    char* ws = (char*)d_ws;
    ushort4* X2b    = (ushort4*)ws; ws += (size_t)N2 * D * 2;          // 12.8 MB, 16B-aligned
    float2*  WgT2g  = (float2*)ws;  ws += AD * 64 * sizeof(float2);
    int*     cnt    = (int*)ws;     ws += N1 * sizeof(int);
    int*     rowptr = (int*)ws;     ws += (N1 + 1) * sizeof(int);
    int*     cursor = (int*)ws;     ws += N1 * sizeof(int);
    int*     csr_dst= (int*)ws;     ws += NE * sizeof(int);
    float*   inv2   = (float*)ws;   ws += N2 * sizeof(float);
    int*     bsum   = (int*)ws;     ws += NSB * sizeof(int);

    pre_kernel<<<16 + NORM_BLKS + NSB, 256, 0, stream>>>(Wg, WgT2g, X2, inv2, X2b, cnt);
    hist_kernel<<<(NE + 255) / 256, 256, 0, stream>>>(src, cnt);
    scan1_kernel<<<NSB, SCAN_BLK, 0, stream>>>(cnt, rowptr, bsum);
    scan23_kernel<<<NSB, SCAN_BLK, 0, stream>>>(rowptr, bsum, cursor);
    fill_kernel<<<(NE + 255) / 256, 256, 0, stream>>>(src, dst, cursor, csr_dst);
    node_kernel<<<N1 / 4, 256, 0, stream>>>(X1, X2b, rowptr, csr_dst, inv2, out);
    gate_kernel<<<(N1 + 63) / 64, 256, 0, stream>>>(Xn, WgT2g, out);
}